// Round 5
// baseline (1473.561 us; speedup 1.0000x reference)
//
#include <hip/hip_runtime.h>
#include <stdint.h>

typedef __attribute__((ext_vector_type(8))) short bhalf8;   // 8 bf16 (4 VGPR)
typedef __attribute__((ext_vector_type(4))) float floatx4;  // 4 f32 acc

#define BM 256
#define BN 128
#define BK 64
#define AST 72   // 144B row stride: 16B-aligned, pad kills read conflicts
#define BST 72
#define NT 512

constexpr int Mdim = 8192;   // B*S
constexpr int Ndim = 11008;
constexpr int Kdim = 4096;
constexpr size_t WT_BYTES = (size_t)Ndim * Kdim * 2;   // 90,177,536

// packed f32x2 -> bf16x2 (RNE). Same helper on A-convert (GEMM) and B-dequant
// (prep), so any src-order quirk is the same k-permutation on both operands
// and cancels in the dot product. Validated end-to-end in round 4.
__device__ __forceinline__ unsigned int cvt_pk_bf16(float lo, float hi) {
  unsigned int r;
  asm("v_cvt_pk_bf16_f32 %0, %1, %2" : "=v"(r) : "v"(lo), "v"(hi));
  return r;
}

// ---------------- prep: dequant qweight -> Wt[N][K] bf16 ----------------
// Block = 256 threads handles tile n in [n0,n0+32), k-words [8y, 8y+8).
// Read phase coalesced along n; LDS transpose; write phase contiguous 128B/row.
__global__ __launch_bounds__(256)
void dequant_wt_kernel(const unsigned int*  __restrict__ qweight,  // (K/8, N)
                       const unsigned int*  __restrict__ qzeros,   // (G, N/8)
                       const float*         __restrict__ scales,   // f32 (G,N)
                       unsigned short*      __restrict__ Wt)       // bf16 (N,K)
{
  __shared__ unsigned short T[32 * AST];   // 32 n-rows x 64 k (+pad)
  const int t  = threadIdx.x;
  const int n0 = (int)(blockIdx.x % (Ndim / 32)) * 32;   // Ndim/32 = 344
  const int y  = (int)(blockIdx.x / (Ndim / 32));        // 0..63

  // read + dequant: lane groups read 2 rows x 32 consecutive words (coalesced)
  const int i  = t >> 5;          // 0..7  (k-word within block's 8)
  const int j  = t & 31;          // n offset
  const int n  = n0 + j;
  const int kw = 8 * y + i;       // k-word row; k = kw*8 .. kw*8+7 (g uniform)
  const int g  = y >> 1;          // (64y..64y+63)>>7

  const unsigned int q  = qweight[(size_t)kw * Ndim + n];
  const float        s  = scales[(size_t)g * Ndim + n];
  const unsigned int qz = qzeros[(size_t)g * (Ndim / 8) + (n >> 3)];
  const float        zc = -(float)((qz >> ((n & 7) * 4)) & 15u) * s;

  uint4 pk;
  {
    unsigned int w[4];
#pragma unroll
    for (int jj = 0; jj < 4; ++jj) {
      const float f0 = fmaf((float)((q >> (8 * jj))     & 15u), s, zc); // sub=2jj
      const float f1 = fmaf((float)((q >> (8 * jj + 4)) & 15u), s, zc); // sub=2jj+1
      w[jj] = cvt_pk_bf16(f0, f1);
    }
    pk.x = w[0]; pk.y = w[1]; pk.z = w[2]; pk.w = w[3];
  }
  *(uint4*)(&T[j * AST + i * 8]) = pk;
  __syncthreads();

  // write: 8 lanes per n-row -> 128B contiguous per row
  const int j2 = t >> 3;          // 0..31 (n)
  const int i2 = t & 7;           // 0..7  (16B chunk along k)
  *(uint4*)(Wt + (size_t)(n0 + j2) * Kdim + (size_t)y * 64 + i2 * 8) =
      *(const uint4*)(&T[j2 * AST + i2 * 8]);
}

// ---------------- main GEMM from precomputed Wt (bf16 B^T) ----------------
__global__ __launch_bounds__(NT, 1)
void qgemm_pre(const float*          __restrict__ x,     // f32 (M,K)
               const unsigned short* __restrict__ Wt,    // bf16 (N,K)
               const float*          __restrict__ bias,  // f32 (N)
               float*                __restrict__ out)   // f32 (M,N)
{
  __shared__ unsigned short As[BM * AST];   // 36864 B
  __shared__ unsigned short Bs[BN * BST];   // 18432 B

  const int tid  = threadIdx.x;
  const int lane = tid & 63;
  const int wid  = tid >> 6;
  const int wm   = wid >> 1;        // 0..3
  const int wn   = wid & 1;         // 0..1
  const int fr   = lane & 15;
  const int kh   = lane >> 4;       // 0..3

  const int nbn = Ndim / BN;                    // 86
  const int nwg = (Mdim / BM) * nbn;            // 2752 (%8==0)
  const int bid = blockIdx.x;
  const int swz = (bid & 7) * (nwg >> 3) + (bid >> 3);
  const int m0  = (swz / nbn) * BM;
  const int n0  = (swz % nbn) * BN;

  // A staging (identical mapping to validated round-4 kernel)
  const int ar = tid >> 3;                 // 0..63
  const int ac = (tid & 7) * 8;            // 0..56
  const float* xbase = x + (size_t)(m0 + ar) * Kdim + ac;

  // B staging: 4 lanes per n-row, each 32B contiguous along k
  const int bn = tid >> 2;                 // 0..127
  const int bq = (tid & 3) * 16;           // elem offset 0,16,32,48
  const unsigned short* wbase = Wt + (size_t)(n0 + bn) * Kdim + bq;

  floatx4 acc[4][4] = {};
  float4 av[4][2];
  uint4  bv[2];

  // prologue: loads for kt=0
#pragma unroll
  for (int i = 0; i < 4; ++i) {
    const float* p = xbase + (size_t)i * 64 * Kdim;
    av[i][0] = *(const float4*)(p);
    av[i][1] = *(const float4*)(p + 4);
  }
  bv[0] = *(const uint4*)(wbase);
  bv[1] = *(const uint4*)(wbase + 8);

  for (int kt = 0; kt < Kdim / BK; ++kt) {
    __syncthreads();   // previous tile's ds_reads complete before overwrite

    // ---- write phase: A cvt f32->bf16, B verbatim ----
#pragma unroll
    for (int i = 0; i < 4; ++i) {
      uint4 pk;
      pk.x = cvt_pk_bf16(av[i][0].x, av[i][0].y);
      pk.y = cvt_pk_bf16(av[i][0].z, av[i][0].w);
      pk.z = cvt_pk_bf16(av[i][1].x, av[i][1].y);
      pk.w = cvt_pk_bf16(av[i][1].z, av[i][1].w);
      *(uint4*)(&As[(ar + i * 64) * AST + ac]) = pk;
    }
    *(uint4*)(&Bs[bn * BST + bq])     = bv[0];
    *(uint4*)(&Bs[bn * BST + bq + 8]) = bv[1];
    __syncthreads();

    // ---- T14: issue next tile's global loads; latency hides under MFMA ----
    if (kt + 1 < Kdim / BK) {
      const int k1 = (kt + 1) * BK;
#pragma unroll
      for (int i = 0; i < 4; ++i) {
        const float* p = xbase + (size_t)i * 64 * Kdim + k1;
        av[i][0] = *(const float4*)(p);
        av[i][1] = *(const float4*)(p + 4);
      }
      bv[0] = *(const uint4*)(wbase + k1);
      bv[1] = *(const uint4*)(wbase + k1 + 8);
    }

    // ---- MFMA: 2 k-steps x 16 ----
#pragma unroll
    for (int ks = 0; ks < BK / 32; ++ks) {
      bhalf8 a[4], b[4];
#pragma unroll
      for (int mi = 0; mi < 4; ++mi)
        a[mi] = *(const bhalf8*)(&As[(wm * 64 + mi * 16 + fr) * AST + ks * 32 + kh * 8]);
#pragma unroll
      for (int ni = 0; ni < 4; ++ni)
        b[ni] = *(const bhalf8*)(&Bs[(wn * 64 + ni * 16 + fr) * BST + ks * 32 + kh * 8]);
#pragma unroll
      for (int mi = 0; mi < 4; ++mi)
#pragma unroll
        for (int ni = 0; ni < 4; ++ni)
          acc[mi][ni] = __builtin_amdgcn_mfma_f32_16x16x32_bf16(a[mi], b[ni], acc[mi][ni], 0, 0, 0);
    }
  }

  // ---- epilogue: +bias, store f32 (C/D: col=lane&15, row=kh*4+e) ----
#pragma unroll
  for (int ni = 0; ni < 4; ++ni) {
    const int col = n0 + wn * 64 + ni * 16 + fr;
    const float bsv = bias[col];
#pragma unroll
    for (int mi = 0; mi < 4; ++mi) {
      const int rowb = m0 + wm * 64 + mi * 16 + kh * 4;
#pragma unroll
      for (int e = 0; e < 4; ++e)
        out[(size_t)(rowb + e) * Ndim + col] = acc[mi][ni][e] + bsv;
    }
  }
}

// ---------------- fallback: round-4 fused kernel (validated) ----------------
__global__ __launch_bounds__(NT, 1)
void qgemm_fused(const float*         __restrict__ x,
                 const unsigned int*  __restrict__ qweight,
                 const unsigned int*  __restrict__ qzeros,
                 const float*         __restrict__ scales,
                 const float*         __restrict__ bias,
                 float*               __restrict__ out)
{
  __shared__ unsigned short As[BM * AST];
  __shared__ unsigned short Bs[BN * BST];

  const int tid  = threadIdx.x;
  const int lane = tid & 63;
  const int wid  = tid >> 6;
  const int wm   = wid >> 1;
  const int wn   = wid & 1;
  const int fr   = lane & 15;
  const int kh   = lane >> 4;

  const int nbn = Ndim / BN;
  const int nwg = (Mdim / BM) * nbn;
  const int bid = blockIdx.x;
  const int swz = (bid & 7) * (nwg >> 3) + (bid >> 3);
  const int m0  = (swz / nbn) * BM;
  const int n0  = (swz % nbn) * BN;

  const int ar = tid >> 3;
  const int ac = (tid & 7) * 8;
  const float* xbase = x + (size_t)(m0 + ar) * Kdim + ac;

  const int bc = tid & 127;
  const int br = tid >> 7;
  const int nn = n0 + bc;

  floatx4 acc[4][4] = {};

  for (int kt = 0; kt < Kdim / BK; ++kt) {
    const int k0 = kt * BK;
    __syncthreads();

    float4 av[4][2];
#pragma unroll
    for (int i = 0; i < 4; ++i) {
      const float* p = xbase + (size_t)i * 64 * Kdim + k0;
      av[i][0] = *(const float4*)(p);
      av[i][1] = *(const float4*)(p + 4);
    }

    const int g = k0 >> 7;
    const float        s  = scales[(size_t)g * Ndim + nn];
    const unsigned int qz = qzeros[(size_t)g * (Ndim / 8) + (nn >> 3)];
    const float        zc = -(float)((qz >> ((nn & 7) * 4)) & 15u) * s;
    unsigned int qv[2];
    qv[0] = qweight[(size_t)(k0 / 8 + br)     * Ndim + nn];
    qv[1] = qweight[(size_t)(k0 / 8 + br + 4) * Ndim + nn];

#pragma unroll
    for (int i = 0; i < 4; ++i) {
      uint4 pk;
      pk.x = cvt_pk_bf16(av[i][0].x, av[i][0].y);
      pk.y = cvt_pk_bf16(av[i][0].z, av[i][0].w);
      pk.z = cvt_pk_bf16(av[i][1].x, av[i][1].y);
      pk.w = cvt_pk_bf16(av[i][1].z, av[i][1].w);
      *(uint4*)(&As[(ar + i * 64) * AST + ac]) = pk;
    }

#pragma unroll
    for (int i = 0; i < 2; ++i) {
      const unsigned int q = qv[i];
      const int r = br + i * 4;
      uint4 pk;
      unsigned int w[4];
#pragma unroll
      for (int j = 0; j < 4; ++j) {
        const float f0 = fmaf((float)((q >> (8 * j))     & 15u), s, zc);
        const float f1 = fmaf((float)((q >> (8 * j + 4)) & 15u), s, zc);
        w[j] = cvt_pk_bf16(f0, f1);
      }
      pk.x = w[0]; pk.y = w[1]; pk.z = w[2]; pk.w = w[3];
      *(uint4*)(&Bs[bc * BST + r * 8]) = pk;
    }
    __syncthreads();

#pragma unroll
    for (int ks = 0; ks < BK / 32; ++ks) {
      bhalf8 a[4], b[4];
#pragma unroll
      for (int mi = 0; mi < 4; ++mi)
        a[mi] = *(const bhalf8*)(&As[(wm * 64 + mi * 16 + fr) * AST + ks * 32 + kh * 8]);
#pragma unroll
      for (int ni = 0; ni < 4; ++ni)
        b[ni] = *(const bhalf8*)(&Bs[(wn * 64 + ni * 16 + fr) * BST + ks * 32 + kh * 8]);
#pragma unroll
      for (int mi = 0; mi < 4; ++mi)
#pragma unroll
        for (int ni = 0; ni < 4; ++ni)
          acc[mi][ni] = __builtin_amdgcn_mfma_f32_16x16x32_bf16(a[mi], b[ni], acc[mi][ni], 0, 0, 0);
    }
  }

#pragma unroll
  for (int ni = 0; ni < 4; ++ni) {
    const int col = n0 + wn * 64 + ni * 16 + fr;
    const float bsv = bias[col];
#pragma unroll
    for (int mi = 0; mi < 4; ++mi) {
      const int rowb = m0 + wm * 64 + mi * 16 + kh * 4;
#pragma unroll
      for (int e = 0; e < 4; ++e)
        out[(size_t)(rowb + e) * Ndim + col] = acc[mi][ni][e] + bsv;
    }
  }
}

extern "C" void kernel_launch(void* const* d_in, const int* in_sizes, int n_in,
                              void* d_out, int out_size, void* d_ws, size_t ws_size,
                              hipStream_t stream) {
  const float*        x       = (const float*)d_in[0];
  const unsigned int* qweight = (const unsigned int*)d_in[1];
  const unsigned int* qzeros  = (const unsigned int*)d_in[2];
  const float*        scales  = (const float*)d_in[3];
  // d_in[4] = g_idx: arange(K)//128, recomputed in-kernel as k>>7
  const float*        bias    = (const float*)d_in[5];
  float*              outp    = (float*)d_out;

  const int nwg = (Mdim / BM) * (Ndim / BN);   // 2752

  if (ws_size >= WT_BYTES) {
    unsigned short* Wt = (unsigned short*)d_ws;
    dequant_wt_kernel<<<dim3((Ndim / 32) * (Kdim / 64)), dim3(256), 0, stream>>>(
        qweight, qzeros, scales, Wt);
    qgemm_pre<<<dim3(nwg), dim3(NT), 0, stream>>>(x, Wt, bias, outp);
  } else {
    qgemm_fused<<<dim3(nwg), dim3(NT), 0, stream>>>(x, qweight, qzeros, scales, bias, outp);
  }
}

// Round 6
// 757.041 us; speedup vs baseline: 1.9465x; 1.9465x over previous
//
#include <hip/hip_runtime.h>
#include <stdint.h>

typedef __attribute__((ext_vector_type(8))) short bhalf8;   // 8 bf16 (4 VGPR)
typedef __attribute__((ext_vector_type(4))) float floatx4;  // 4 f32 acc

#define BM 256
#define BN 128
#define BK 64
#define AST 72   // fallback kernel's padded A stride
#define BST 72   // B stride (padded): reads ~2-way (free)
#define NT 512

constexpr int Mdim = 8192;   // B*S
constexpr int Ndim = 11008;
constexpr int Kdim = 4096;
constexpr size_t XB_BYTES = (size_t)Mdim * Kdim * 2;   // 67,108,864

// packed f32x2 -> bf16x2 (RNE), single VALU inst (validated round 4)
__device__ __forceinline__ unsigned int cvt_pk_bf16(float lo, float hi) {
  unsigned int r;
  asm("v_cvt_pk_bf16_f32 %0, %1, %2" : "=v"(r) : "v"(lo), "v"(hi));
  return r;
}

// ---------------- prep: x f32 -> bf16 (memory-bound, ~40us) ----------------
__global__ __launch_bounds__(256)
void cvt_x_kernel(const float* __restrict__ x, unsigned short* __restrict__ xb) {
  const int nchunk = Mdim * Kdim / 8;            // 4,194,304
  const int stride = 2048 * 256;
  for (int c = blockIdx.x * 256 + threadIdx.x; c < nchunk; c += stride) {
    const float4 f0 = *(const float4*)(x + (size_t)c * 8);
    const float4 f1 = *(const float4*)(x + (size_t)c * 8 + 4);
    uint4 pk;
    pk.x = cvt_pk_bf16(f0.x, f0.y);
    pk.y = cvt_pk_bf16(f0.z, f0.w);
    pk.z = cvt_pk_bf16(f1.x, f1.y);
    pk.w = cvt_pk_bf16(f1.z, f1.w);
    *(uint4*)(xb + (size_t)c * 8) = pk;
  }
}

// ------------- main: fused dequant GEMM, A via global_load_lds -------------
// As layout: linear [row][64], XOR-swizzled at 16B-chunk granularity:
//   physical chunk slot p of row r holds logical chunk q = p ^ (r&7).
// Writes: DMA linear dest + pre-swizzled global source (rule #21).
// Reads:  same XOR on the ds_read address.
__global__ __launch_bounds__(NT, 1)
void qgemm_dma(const unsigned short* __restrict__ xb,      // bf16 (M,K) in ws
               const unsigned int*   __restrict__ qweight, // (K/8, N)
               const unsigned int*   __restrict__ qzeros,  // (G, N/8)
               const float*          __restrict__ scales,  // f32 (G,N)
               const float*          __restrict__ bias,    // f32 (N)
               float*                __restrict__ out)     // f32 (M,N)
{
  __shared__ unsigned short As[BM * BK];    // 32768 B, linear (DMA dest)
  __shared__ unsigned short Bs[BN * BST];   // 18432 B, padded

  const int tid  = threadIdx.x;
  const int lane = tid & 63;
  const int wid  = tid >> 6;
  const int wm   = wid >> 1;        // 0..3
  const int wn   = wid & 1;         // 0..1
  const int fr   = lane & 15;
  const int kh   = lane >> 4;       // 0..3

  const int nbn = Ndim / BN;                    // 86
  const int nwg = (Mdim / BM) * nbn;            // 2752 (%8==0)
  const int bid = blockIdx.x;
  const int swz = (bid & 7) * (nwg >> 3) + (bid >> 3);
  const int m0  = (swz / nbn) * BM;
  const int n0  = (swz % nbn) * BN;

  // A DMA source mapping: chunk c = i*NT+tid -> row=c>>3, slot=c&7,
  // logical q = slot ^ (row&7); source = xb[m0+row][k0 + q*8]
  const unsigned short* asrc[4];
#pragma unroll
  for (int i = 0; i < 4; ++i) {
    const int c   = i * NT + tid;
    const int row = c >> 3;
    const int q   = (c & 7) ^ (row & 7);
    asrc[i] = xb + (size_t)(m0 + row) * Kdim + q * 8;
  }

  // B staging: 2 int32/thread, same column nn (shared scale/zero)
  const int bc = tid & 127;                // n within tile
  const int br = tid >> 7;                 // 0..3; second row = br+4
  const int nn = n0 + bc;

  floatx4 acc[4][4] = {};

  for (int kt = 0; kt < Kdim / BK; ++kt) {
    const int k0 = kt * BK;
    __syncthreads();   // previous tile's ds_reads complete before overwrite

    // ---- A: 4x async DMA global->LDS, 16B/lane, linear dest ----
#pragma unroll
    for (int i = 0; i < 4; ++i) {
      __builtin_amdgcn_global_load_lds(
          (const __attribute__((address_space(1))) void*)(asrc[i] + k0),
          (__attribute__((address_space(3))) void*)(&As[(i * NT + tid) * 8]),
          16, 0, 0);
    }

    // ---- B: load + fused dequant -> LDS (validated round-4 path) ----
    const int g = k0 >> 7;   // GROUPSIZE=128, uniform within K-tile
    const float        s  = scales[(size_t)g * Ndim + nn];
    const unsigned int qz = qzeros[(size_t)g * (Ndim / 8) + (nn >> 3)];
    const float        zc = -(float)((qz >> ((nn & 7) * 4)) & 15u) * s;
    unsigned int qv[2];
    qv[0] = qweight[(size_t)(k0 / 8 + br)     * Ndim + nn];
    qv[1] = qweight[(size_t)(k0 / 8 + br + 4) * Ndim + nn];

#pragma unroll
    for (int i = 0; i < 2; ++i) {
      const unsigned int q = qv[i];
      const int r = br + i * 4;            // k-octet within tile
      uint4 pk;
      unsigned int w[4];
#pragma unroll
      for (int j = 0; j < 4; ++j) {
        const float f0 = fmaf((float)((q >> (8 * j))     & 15u), s, zc); // k=8r+2j
        const float f1 = fmaf((float)((q >> (8 * j + 4)) & 15u), s, zc); // k=8r+2j+1
        w[j] = cvt_pk_bf16(f0, f1);
      }
      pk.x = w[0]; pk.y = w[1]; pk.z = w[2]; pk.w = w[3];
      *(uint4*)(&Bs[bc * BST + r * 8]) = pk;   // ds_write_b128
    }
    __syncthreads();   // drains vmcnt (A DMA) + lgkm (B writes)

    // ---- MFMA: 2 k-steps x 16 ----
#pragma unroll
    for (int ks = 0; ks < BK / 32; ++ks) {
      const int qa = (((ks * 4 + kh) ^ (fr & 7)) << 3);   // swizzled A chunk
      bhalf8 a[4], b[4];
#pragma unroll
      for (int mi = 0; mi < 4; ++mi)
        a[mi] = *(const bhalf8*)(&As[(wm * 64 + mi * 16 + fr) * BK + qa]);
#pragma unroll
      for (int ni = 0; ni < 4; ++ni)
        b[ni] = *(const bhalf8*)(&Bs[(wn * 64 + ni * 16 + fr) * BST + ks * 32 + kh * 8]);
#pragma unroll
      for (int mi = 0; mi < 4; ++mi)
#pragma unroll
        for (int ni = 0; ni < 4; ++ni)
          acc[mi][ni] = __builtin_amdgcn_mfma_f32_16x16x32_bf16(a[mi], b[ni], acc[mi][ni], 0, 0, 0);
    }
  }

  // ---- epilogue: +bias, store f32 (C/D: col=lane&15, row=kh*4+e) ----
#pragma unroll
  for (int ni = 0; ni < 4; ++ni) {
    const int col = n0 + wn * 64 + ni * 16 + fr;
    const float bsv = bias[col];
#pragma unroll
    for (int mi = 0; mi < 4; ++mi) {
      const int rowb = m0 + wm * 64 + mi * 16 + kh * 4;
#pragma unroll
      for (int e = 0; e < 4; ++e)
        out[(size_t)(rowb + e) * Ndim + col] = acc[mi][ni][e] + bsv;
    }
  }
}

// ---------------- fallback: round-4 fused kernel (validated, 950us) --------
__global__ __launch_bounds__(NT, 1)
void qgemm_fused(const float*         __restrict__ x,
                 const unsigned int*  __restrict__ qweight,
                 const unsigned int*  __restrict__ qzeros,
                 const float*         __restrict__ scales,
                 const float*         __restrict__ bias,
                 float*               __restrict__ out)
{
  __shared__ unsigned short As[BM * AST];
  __shared__ unsigned short Bs[BN * BST];

  const int tid  = threadIdx.x;
  const int lane = tid & 63;
  const int wid  = tid >> 6;
  const int wm   = wid >> 1;
  const int wn   = wid & 1;
  const int fr   = lane & 15;
  const int kh   = lane >> 4;

  const int nbn = Ndim / BN;
  const int nwg = (Mdim / BM) * nbn;
  const int bid = blockIdx.x;
  const int swz = (bid & 7) * (nwg >> 3) + (bid >> 3);
  const int m0  = (swz / nbn) * BM;
  const int n0  = (swz % nbn) * BN;

  const int ar = tid >> 3;
  const int ac = (tid & 7) * 8;
  const float* xbase = x + (size_t)(m0 + ar) * Kdim + ac;

  const int bc = tid & 127;
  const int br = tid >> 7;
  const int nn = n0 + bc;

  floatx4 acc[4][4] = {};

  for (int kt = 0; kt < Kdim / BK; ++kt) {
    const int k0 = kt * BK;
    __syncthreads();

    float4 av[4][2];
#pragma unroll
    for (int i = 0; i < 4; ++i) {
      const float* p = xbase + (size_t)i * 64 * Kdim + k0;
      av[i][0] = *(const float4*)(p);
      av[i][1] = *(const float4*)(p + 4);
    }

    const int g = k0 >> 7;
    const float        s  = scales[(size_t)g * Ndim + nn];
    const unsigned int qz = qzeros[(size_t)g * (Ndim / 8) + (nn >> 3)];
    const float        zc = -(float)((qz >> ((nn & 7) * 4)) & 15u) * s;
    unsigned int qv[2];
    qv[0] = qweight[(size_t)(k0 / 8 + br)     * Ndim + nn];
    qv[1] = qweight[(size_t)(k0 / 8 + br + 4) * Ndim + nn];

#pragma unroll
    for (int i = 0; i < 4; ++i) {
      uint4 pk;
      pk.x = cvt_pk_bf16(av[i][0].x, av[i][0].y);
      pk.y = cvt_pk_bf16(av[i][0].z, av[i][0].w);
      pk.z = cvt_pk_bf16(av[i][1].x, av[i][1].y);
      pk.w = cvt_pk_bf16(av[i][1].z, av[i][1].w);
      *(uint4*)(&As[(ar + i * 64) * AST + ac]) = pk;
    }

#pragma unroll
    for (int i = 0; i < 2; ++i) {
      const unsigned int q = qv[i];
      const int r = br + i * 4;
      uint4 pk;
      unsigned int w[4];
#pragma unroll
      for (int j = 0; j < 4; ++j) {
        const float f0 = fmaf((float)((q >> (8 * j))     & 15u), s, zc);
        const float f1 = fmaf((float)((q >> (8 * j + 4)) & 15u), s, zc);
        w[j] = cvt_pk_bf16(f0, f1);
      }
      pk.x = w[0]; pk.y = w[1]; pk.z = w[2]; pk.w = w[3];
      *(uint4*)(&Bs[bc * BST + r * 8]) = pk;
    }
    __syncthreads();

#pragma unroll
    for (int ks = 0; ks < BK / 32; ++ks) {
      bhalf8 a[4], b[4];
#pragma unroll
      for (int mi = 0; mi < 4; ++mi)
        a[mi] = *(const bhalf8*)(&As[(wm * 64 + mi * 16 + fr) * AST + ks * 32 + kh * 8]);
#pragma unroll
      for (int ni = 0; ni < 4; ++ni)
        b[ni] = *(const bhalf8*)(&Bs[(wn * 64 + ni * 16 + fr) * BST + ks * 32 + kh * 8]);
#pragma unroll
      for (int mi = 0; mi < 4; ++mi)
#pragma unroll
        for (int ni = 0; ni < 4; ++ni)
          acc[mi][ni] = __builtin_amdgcn_mfma_f32_16x16x32_bf16(a[mi], b[ni], acc[mi][ni], 0, 0, 0);
    }
  }

#pragma unroll
  for (int ni = 0; ni < 4; ++ni) {
    const int col = n0 + wn * 64 + ni * 16 + fr;
    const float bsv = bias[col];
#pragma unroll
    for (int mi = 0; mi < 4; ++mi) {
      const int rowb = m0 + wm * 64 + mi * 16 + kh * 4;
#pragma unroll
      for (int e = 0; e < 4; ++e)
        out[(size_t)(rowb + e) * Ndim + col] = acc[mi][ni][e] + bsv;
    }
  }
}

extern "C" void kernel_launch(void* const* d_in, const int* in_sizes, int n_in,
                              void* d_out, int out_size, void* d_ws, size_t ws_size,
                              hipStream_t stream) {
  const float*        x       = (const float*)d_in[0];
  const unsigned int* qweight = (const unsigned int*)d_in[1];
  const unsigned int* qzeros  = (const unsigned int*)d_in[2];
  const float*        scales  = (const float*)d_in[3];
  // d_in[4] = g_idx: arange(K)//128, recomputed in-kernel as k>>7
  const float*        bias    = (const float*)d_in[5];
  float*              outp    = (float*)d_out;

  const int nwg = (Mdim / BM) * (Ndim / BN);   // 2752

  if (ws_size >= XB_BYTES) {
    unsigned short* xb = (unsigned short*)d_ws;
    cvt_x_kernel<<<dim3(2048), dim3(256), 0, stream>>>(x, xb);
    qgemm_dma<<<dim3(nwg), dim3(NT), 0, stream>>>(xb, qweight, qzeros, scales, bias, outp);
  } else {
    qgemm_fused<<<dim3(nwg), dim3(NT), 0, stream>>>(x, qweight, qzeros, scales, bias, outp);
  }
}